// Round 15
// baseline (1742.760 us; speedup 1.0000x reference)
//
#include <hip/hip_runtime.h>
#include <hip/hip_bf16.h>
#include <hip/hip_fp16.h>

using half2_t = __attribute__((ext_vector_type(2))) _Float16;
using half8_t = __attribute__((ext_vector_type(8))) _Float16;
using f32x4   = __attribute__((ext_vector_type(4))) float;
using i32x4   = __attribute__((ext_vector_type(4))) int;

#define B_   64
#define T_   2048
#define D_   256
#define U_   256
#define NG   768
#define TC   512
#define NCHUNK (T_/TC)
#define GB_SCAN 16     // scan blocks (4 batches each)
#define GB_GEMM 1536
#define GB_LN   2048
#define LOG2E 1.4426950408889634f

typedef const __attribute__((address_space(1))) void* gptr_t;
typedef __attribute__((address_space(3))) void* lptr_t;

__device__ __forceinline__ float rcpf(float x) { return __builtin_amdgcn_rcpf(x); }

// barrier that waits ONLY on LDS ops (no vmcnt(0) drain of global store/prefetch)
__device__ __forceinline__ void bar_lds() {
  asm volatile("s_waitcnt lgkmcnt(0)\n\ts_barrier" ::: "memory");
}

// ---------------- prep kernels ----------------

__global__ void conv_x_chunk(const float* __restrict__ x, _Float16* __restrict__ xh, int t0) {
  size_t idx = ((size_t)blockIdx.x * 256 + threadIdx.x) * 8;
  int b   = (int)(idx >> 17);
  int rem = (int)(idx & 131071);
  const float4* p = (const float4*)(x + ((size_t)(b * T_ + t0)) * D_ + rem);
  float4 v0 = p[0], v1 = p[1];
  half8_t o;
  o[0] = (_Float16)v0.x; o[1] = (_Float16)v0.y; o[2] = (_Float16)v0.z; o[3] = (_Float16)v0.w;
  o[4] = (_Float16)v1.x; o[5] = (_Float16)v1.y; o[6] = (_Float16)v1.z; o[7] = (_Float16)v1.w;
  *(half8_t*)(xh + idx) = o;
}

__global__ void conv_T(const float* __restrict__ src, _Float16* __restrict__ dst) {
  int idx = blockIdx.x * 256 + threadIdx.x;
  int d = idx / NG;
  int j = idx - d * NG;
  dst[j * 256 + d] = (_Float16)src[idx];
}

__global__ void init_scale(unsigned* s) { if (threadIdx.x == 0) *s = 0u; }

__global__ void absmax_rec(const float* __restrict__ rec, unsigned* __restrict__ s) {
  int i = (blockIdx.x * 256 + threadIdx.x) * 4;
  float4 v = *(const float4*)(rec + i);
  float m = fmaxf(fmaxf(fabsf(v.x), fabsf(v.y)), fmaxf(fabsf(v.z), fabsf(v.w)));
  #pragma unroll
  for (int off = 32; off >= 1; off >>= 1) m = fmaxf(m, __shfl_xor(m, off));
  __shared__ float sm[4];
  int l = threadIdx.x & 63, wv = threadIdx.x >> 6;
  if (l == 0) sm[wv] = m;
  __syncthreads();
  if (threadIdx.x == 0) {
    m = fmaxf(fmaxf(sm[0], sm[1]), fmaxf(sm[2], sm[3]));
    atomicMax(s, __float_as_uint(m));
  }
}

// rec [256][768] f32 -> i8 A-fragment layout [48 mt][4 ks][64 lane][16B]
__global__ void conv_rec_i8(const float* __restrict__ rec, const unsigned* __restrict__ sc,
                            char* __restrict__ dst) {
  int idx = blockIdx.x * 256 + threadIdx.x;
  int j = idx & 15, l = (idx >> 4) & 63, sl = idx >> 10;
  int mt = sl >> 2, ks = sl & 3, bi = l & 15, hi = l >> 4;
  float am = __uint_as_float(*sc) + 1e-30f;
  float s = 127.f / am;
  float v = rec[(size_t)(ks * 64 + hi * 16 + j) * NG + mt * 16 + bi] * s;
  int q = __float2int_rn(v);
  q = q > 127 ? 127 : (q < -127 ? -127 : q);
  dst[idx] = (char)q;
}

// ---------------- mega kernel: [scan | gemm | ln] by blockIdx range ----------------
// xws page layout per (g,t): 3072 f16 = 6144 B: [0,4096)B zr pairs (lane*4B, pre-scaled by log2e),
//                                               [4096,6144)B h (lane*2B)
// Hq swizzle: granule g of row bc stored at position g ^ (bc<<2)

__global__ __launch_bounds__(1024) void mega(
    const char* __restrict__ rq,        // [48][4][64][16] i8
    const _Float16* __restrict__ xwsS,
    const unsigned* __restrict__ sc,
    float* __restrict__ out,
    float* __restrict__ hg,
    int scanT0,
    const _Float16* __restrict__ xhc,
    const _Float16* __restrict__ kT,
    const float* __restrict__ bias,
    _Float16* __restrict__ xwsG,
    const float* __restrict__ gamma,
    const float* __restrict__ beta,
    int lnT0,
    int nScan, int nGemm)
{
  __shared__ union UU {
    struct { alignas(16) char Hq[2][1024]; } s;
    struct { alignas(16) _Float16 As[128 * 32]; alignas(16) _Float16 Bs[128 * 32]; } g;
  } U;

  int bid = blockIdx.x;
  const int tid = threadIdx.x;

  // ================= SCAN =================
  if (bid < nScan) {
    const int g = bid;
    const int w = tid >> 6, l = tid & 63, bi = l & 15, hi = l >> 4;
    const int bc = bi & 3, qq = bi >> 2;
    const int u = w * 16 + hi * 4 + qq;

    // A-frags: 12 named i32x4 (48 VGPR)
    const i32x4* rp = (const i32x4*)rq;
#define FR(mt, ks) rp[((mt) * 4 + (ks)) * 64 + l]
    i32x4 Az0 = FR(w, 0),      Az1 = FR(w, 1),      Az2 = FR(w, 2),      Az3 = FR(w, 3);
    i32x4 Ar0 = FR(16 + w, 0), Ar1 = FR(16 + w, 1), Ar2 = FR(16 + w, 2), Ar3 = FR(16 + w, 3);
    i32x4 Ah0 = FR(32 + w, 0), Ah1 = FR(32 + w, 1), Ah2 = FR(32 + w, 2), Ah3 = FR(32 + w, 3);
#undef FR
    asm volatile("" : "+v"(Az0), "+v"(Az1), "+v"(Az2), "+v"(Az3),
                      "+v"(Ar0), "+v"(Ar1), "+v"(Ar2), "+v"(Ar3),
                      "+v"(Ah0), "+v"(Ah1), "+v"(Ah2), "+v"(Ah3));

    const float am = __uint_as_float(*sc) + 1e-30f;
    const float dq   = am / (127.f * 127.f);          // h-hat path (linear)
    const float dqzr = dq * LOG2E;                     // z/r path (feeds exp2)

    float h = (scanT0 == 0) ? 0.f : hg[(size_t)(g * 4 + bc) * 256 + u];

    // bank-balanced swizzle: position = granule ^ (bc<<2)
    const int hwa = bc * 256 + ((w ^ (bc << 2)) << 4) + hi * 4 + qq;
    { int q8 = __float2int_rn(h * 127.f); U.s.Hq[0][hwa] = (char)q8; }

    // strength-reduced pointers: advance by one 6144B page per step
    const char* xpz = (const char*)xwsS + (size_t)g * TC * 6144 + tid * 4;
    const char* xph = xpz - tid * 4 + 4096 + tid * 2;
    float* outp = out + ((size_t)(g * 4 + bc) * T_ + scanT0) * U_ + u;

    unsigned nzr = *(const unsigned*)xpz;
    _Float16 nh2 = *(const _Float16*)xph;
    int hrd = 0;   // read-buffer byte offset, toggled by ^1024
    bar_lds();

    #pragma unroll 1
    for (int t = 0; t < TC; ++t) {
      half2_t zrp = __builtin_bit_cast(half2_t, nzr);
      float xzf = (float)zrp[0], xrf = (float)zrp[1], xhf = (float)nh2;
      // unconditional prefetch of next page (last iter over-reads into adjacent ws)
      xpz += 6144; xph += 6144;
      nzr = *(const unsigned*)xpz;
      nh2 = *(const _Float16*)xph;

      const char* hb = &U.s.Hq[0][0] + hrd;
#define BADDR(ks) (bc * 256 + ((((ks) * 4 + hi) ^ (bc << 2)) << 4))
      // load all 4 B-frags up front, then gate-ordered MFMA chains so z/r
      // sigmoid VALU overlaps the remaining MFMA issue
      i32x4 Bf0 = *(const i32x4*)(hb + BADDR(0));
      i32x4 Bf1 = *(const i32x4*)(hb + BADDR(1));
      i32x4 Bf2 = *(const i32x4*)(hb + BADDR(2));
      i32x4 Bf3 = *(const i32x4*)(hb + BADDR(3));
#undef BADDR
      i32x4 az = {}, ar = {}, ah = {};
      az = __builtin_amdgcn_mfma_i32_16x16x64_i8(Az0, Bf0, az, 0, 0, 0);
      az = __builtin_amdgcn_mfma_i32_16x16x64_i8(Az1, Bf1, az, 0, 0, 0);
      az = __builtin_amdgcn_mfma_i32_16x16x64_i8(Az2, Bf2, az, 0, 0, 0);
      az = __builtin_amdgcn_mfma_i32_16x16x64_i8(Az3, Bf3, az, 0, 0, 0);
      ar = __builtin_amdgcn_mfma_i32_16x16x64_i8(Ar0, Bf0, ar, 0, 0, 0);
      ar = __builtin_amdgcn_mfma_i32_16x16x64_i8(Ar1, Bf1, ar, 0, 0, 0);
      ar = __builtin_amdgcn_mfma_i32_16x16x64_i8(Ar2, Bf2, ar, 0, 0, 0);
      ar = __builtin_amdgcn_mfma_i32_16x16x64_i8(Ar3, Bf3, ar, 0, 0, 0);
      ah = __builtin_amdgcn_mfma_i32_16x16x64_i8(Ah0, Bf0, ah, 0, 0, 0);
      ah = __builtin_amdgcn_mfma_i32_16x16x64_i8(Ah1, Bf1, ah, 0, 0, 0);
      ah = __builtin_amdgcn_mfma_i32_16x16x64_i8(Ah2, Bf2, ah, 0, 0, 0);
      ah = __builtin_amdgcn_mfma_i32_16x16x64_i8(Ah3, Bf3, ah, 0, 0, 0);

#define SEL4(a) ((qq & 2) ? ((qq & 1) ? (a)[3] : (a)[2]) : ((qq & 1) ? (a)[1] : (a)[0]))
      float pz = (float)SEL4(az) * dqzr + xzf;        // already in log2 units
      float z  = rcpf(1.f + exp2f(-pz));
      float pr = (float)SEL4(ar) * dqzr + xrf;
      float r  = rcpf(1.f + exp2f(-pr));
      float ph = (float)SEL4(ah) * dq + xhf;
#undef SEL4
      float y  = r * (ph - h) + h;
      float th = 2.f * rcpf(1.f + exp2f(-y * (2.f * LOG2E))) - 1.f;
      h = z * (h - th) + th;

      *outp = h;
      outp += U_;
      int q8 = __float2int_rn(h * 127.f);
      U.s.Hq[0][(hrd ^ 1024) + hwa] = (char)q8;
      hrd ^= 1024;
      bar_lds();
    }

    hg[(size_t)(g * 4 + bc) * 256 + u] = h;
    return;
  }
  bid -= nScan;

  // ================= GEMM =================
  if (bid < nGemm) {
    const int tile = bid;
    const int mt = tile / 6, nt = tile % 6;
    const int w = tid >> 6, l = tid & 63;
    const int wm = (w & 3) * 32, wn = (w >> 2) * 32;
    const char* Ab = (const char*)xhc + (size_t)mt * 128 * 512;
    const char* Bb = (const char*)kT  + (size_t)nt * 128 * 512;
    f32x4 acc[2][2] = {};

    const bool isA = tid < 512;
    const int cc = isA ? tid : tid - 512;
    const int srow = cc >> 2, sgq = cc & 3;
    const int sgs = sgq ^ ((srow >> 1) & 3);
    const char* sb = isA ? Ab : Bb;
    char* ldsb = (char*)(isA ? U.g.As : U.g.Bs) + cc * 16;

    for (int kt = 0; kt < 8; ++kt) {
      __builtin_amdgcn_global_load_lds(
        (gptr_t)(sb + (size_t)srow * 512 + kt * 64 + sgs * 16),
        (lptr_t)ldsb, 16, 0, 0);
      __syncthreads();

      half8_t av[2], bv[2];
      #pragma unroll
      for (int mi = 0; mi < 2; ++mi) {
        int row = wm + mi * 16 + (l & 15);
        int off = row * 64 + (((l >> 4) ^ ((row >> 1) & 3)) << 4);
        av[mi] = *(const half8_t*)((const char*)U.g.As + off);
      }
      #pragma unroll
      for (int ni = 0; ni < 2; ++ni) {
        int row = wn + ni * 16 + (l & 15);
        int off = row * 64 + (((l >> 4) ^ ((row >> 1) & 3)) << 4);
        bv[ni] = *(const half8_t*)((const char*)U.g.Bs + off);
      }
      #pragma unroll
      for (int mi = 0; mi < 2; ++mi)
        #pragma unroll
        for (int ni = 0; ni < 2; ++ni)
          acc[mi][ni] = __builtin_amdgcn_mfma_f32_16x16x32_f16(av[mi], bv[ni], acc[mi][ni], 0, 0, 0);
      __syncthreads();
    }

    // epilogue: scatter to scan page layout with bias add; z/r pre-scaled by log2e
    #pragma unroll
    for (int mi = 0; mi < 2; ++mi) {
      #pragma unroll
      for (int ni = 0; ni < 2; ++ni) {
        int c = nt * 128 + wn + ni * 16 + (l & 15);
        int cgate = c >> 8, uu = c & 255;
        int wv = uu >> 4, hq = (uu >> 2) & 3, qv = uu & 3;
        int lane_tid = wv * 64 + (qv << 2) + (hq << 4);
        float bc = bias[c];
        #pragma unroll
        for (int q = 0; q < 4; ++q) {
          int arow = mt * 128 + wm + mi * 16 + ((l >> 4) * 4 + q);
          int b = arow >> 9, tloc = arow & 511;
          int g = b >> 2, bidx = b & 3;
          int lane = lane_tid + bidx;
          size_t page = (size_t)(g * 512 + tloc) * 3072;
          float vv = acc[mi][ni][q] + bc;
          size_t dst;
          if (cgate < 2) { vv *= LOG2E; dst = page + (size_t)lane * 2 + cgate; }
          else           { dst = page + 2048 + lane; }
          xwsG[dst] = (_Float16)vv;
        }
      }
    }
    return;
  }
  bid -= nGemm;

  // ================= LN (in-place on out) =================
  {
    int rid = bid * 16 + (tid >> 6);
    int l = tid & 63;
    int b = rid >> 9, tl = rid & 511;
    float* p = out + ((size_t)b * T_ + lnT0 + tl) * U_ + l * 4;
    f32x4 v = *(const f32x4*)p;
    float s  = (v[0] + v[1]) + (v[2] + v[3]);
    float s2 = (v[0]*v[0] + v[1]*v[1]) + (v[2]*v[2] + v[3]*v[3]);
    #pragma unroll
    for (int off = 1; off <= 32; off <<= 1) {
      s  += __shfl_xor(s, off);
      s2 += __shfl_xor(s2, off);
    }
    float mu = s * (1.f / 256.f);
    float var = s2 * (1.f / 256.f) - mu * mu;
    float rs = rsqrtf(var + 1e-6f);
    f32x4 gm = *(const f32x4*)(gamma + l * 4);
    f32x4 bt = *(const f32x4*)(beta + l * 4);
    f32x4 o;
    o[0] = (v[0] - mu) * rs * gm[0] + bt[0];
    o[1] = (v[1] - mu) * rs * gm[1] + bt[1];
    o[2] = (v[2] - mu) * rs * gm[2] + bt[2];
    o[3] = (v[3] - mu) * rs * gm[3] + bt[3];
    *(f32x4*)p = o;
  }
}

// ---------------- launcher ----------------
extern "C" void kernel_launch(void* const* d_in, const int* in_sizes, int n_in,
                              void* d_out, int out_size, void* d_ws, size_t ws_size,
                              hipStream_t stream) {
  const float* x     = (const float*)d_in[0];
  const float* kern  = (const float*)d_in[1];
  const float* rec   = (const float*)d_in[2];
  const float* bias  = (const float*)d_in[3];
  const float* gamma = (const float*)d_in[4];
  const float* beta  = (const float*)d_in[5];
  float* out = (float*)d_out;
  char* ws = (char*)d_ws;

  const size_t XWS = 50331648;  // 16*512*3072*2
  const bool pipe = (ws_size >= 118096000ull);

  _Float16* xwsA = (_Float16*)ws;
  _Float16* xwsB = pipe ? (_Float16*)(ws + XWS) : xwsA;
  size_t o = pipe ? 2 * XWS : XWS;
  _Float16* xhc = (_Float16*)(ws + o);           o += 16777216;
  _Float16* kT  = (_Float16*)(ws + o);           o += 393216;
  char*     rq  = (char*)    (ws + o);           o += 196608;
  unsigned* sc  = (unsigned*)(ws + o);           o += 128;
  float*    hg  = (float*)   (ws + o);

  init_scale<<<1, 64, 0, stream>>>(sc);
  absmax_rec<<<192, 256, 0, stream>>>(rec, sc);
  conv_T<<<768, 256, 0, stream>>>(kern, kT);
  conv_rec_i8<<<768, 256, 0, stream>>>(rec, sc, rq);

  if (pipe) {
    conv_x_chunk<<<4096, 256, 0, stream>>>(x, xhc, 0);
    mega<<<GB_GEMM, 1024, 0, stream>>>(rq, xwsA, sc, out, hg, 0,
                                       xhc, kT, bias, xwsA, gamma, beta, 0,
                                       0, GB_GEMM);
    conv_x_chunk<<<4096, 256, 0, stream>>>(x, xhc, TC);
    mega<<<GB_SCAN + GB_GEMM, 1024, 0, stream>>>(rq, xwsA, sc, out, hg, 0,
                                       xhc, kT, bias, xwsB, gamma, beta, 0,
                                       GB_SCAN, GB_GEMM);
    conv_x_chunk<<<4096, 256, 0, stream>>>(x, xhc, 2 * TC);
    mega<<<GB_SCAN + GB_GEMM + GB_LN, 1024, 0, stream>>>(rq, xwsB, sc, out, hg, TC,
                                       xhc, kT, bias, xwsA, gamma, beta, 0,
                                       GB_SCAN, GB_GEMM);
    conv_x_chunk<<<4096, 256, 0, stream>>>(x, xhc, 3 * TC);
    mega<<<GB_SCAN + GB_GEMM + GB_LN, 1024, 0, stream>>>(rq, xwsA, sc, out, hg, 2 * TC,
                                       xhc, kT, bias, xwsB, gamma, beta, TC,
                                       GB_SCAN, GB_GEMM);
    mega<<<GB_SCAN + GB_LN, 1024, 0, stream>>>(rq, xwsB, sc, out, hg, 3 * TC,
                                       xhc, kT, bias, xwsA, gamma, beta, 2 * TC,
                                       GB_SCAN, 0);
    mega<<<GB_LN, 1024, 0, stream>>>(rq, xwsA, sc, out, hg, 0,
                                       xhc, kT, bias, xwsA, gamma, beta, 3 * TC,
                                       0, 0);
  } else {
    for (int c = 0; c < NCHUNK; ++c) {
      int t0 = c * TC;
      conv_x_chunk<<<4096, 256, 0, stream>>>(x, xhc, t0);
      mega<<<GB_GEMM, 1024, 0, stream>>>(rq, xwsA, sc, out, hg, t0,
                                         xhc, kT, bias, xwsA, gamma, beta, t0,
                                         0, GB_GEMM);
      mega<<<GB_SCAN, 1024, 0, stream>>>(rq, xwsA, sc, out, hg, t0,
                                         xhc, kT, bias, xwsA, gamma, beta, t0,
                                         GB_SCAN, 0);
      mega<<<GB_LN, 1024, 0, stream>>>(rq, xwsA, sc, out, hg, t0,
                                       xhc, kT, bias, xwsA, gamma, beta, t0,
                                       0, 0);
    }
  }
}

// Round 16
// 1436.258 us; speedup vs baseline: 1.2134x; 1.2134x over previous
//
#include <hip/hip_runtime.h>
#include <hip/hip_bf16.h>
#include <hip/hip_fp16.h>

using half2_t = __attribute__((ext_vector_type(2))) _Float16;
using half8_t = __attribute__((ext_vector_type(8))) _Float16;
using f32x4   = __attribute__((ext_vector_type(4))) float;
using i32x4   = __attribute__((ext_vector_type(4))) int;

#define B_   64
#define T_   2048
#define D_   256
#define U_   256
#define NG   768
#define TC   512
#define NCHUNK (T_/TC)
#define GB_SCAN 16     // scan blocks (4 batches each)
#define GB_GEMM 1536
#define GB_LN   2048

typedef const __attribute__((address_space(1))) void* gptr_t;
typedef __attribute__((address_space(3))) void* lptr_t;

__device__ __forceinline__ float rcpf(float x) { return __builtin_amdgcn_rcpf(x); }

// barrier that waits ONLY on LDS ops (no vmcnt(0) drain of global store/prefetch)
__device__ __forceinline__ void bar_lds() {
  asm volatile("s_waitcnt lgkmcnt(0)\n\ts_barrier" ::: "memory");
}

// ---------------- prep kernels ----------------

__global__ void conv_x_chunk(const float* __restrict__ x, _Float16* __restrict__ xh, int t0) {
  size_t idx = ((size_t)blockIdx.x * 256 + threadIdx.x) * 8;
  int b   = (int)(idx >> 17);
  int rem = (int)(idx & 131071);
  const float4* p = (const float4*)(x + ((size_t)(b * T_ + t0)) * D_ + rem);
  float4 v0 = p[0], v1 = p[1];
  half8_t o;
  o[0] = (_Float16)v0.x; o[1] = (_Float16)v0.y; o[2] = (_Float16)v0.z; o[3] = (_Float16)v0.w;
  o[4] = (_Float16)v1.x; o[5] = (_Float16)v1.y; o[6] = (_Float16)v1.z; o[7] = (_Float16)v1.w;
  *(half8_t*)(xh + idx) = o;
}

__global__ void conv_T(const float* __restrict__ src, _Float16* __restrict__ dst) {
  int idx = blockIdx.x * 256 + threadIdx.x;
  int d = idx / NG;
  int j = idx - d * NG;
  dst[j * 256 + d] = (_Float16)src[idx];
}

__global__ void init_scale(unsigned* s) { if (threadIdx.x == 0) *s = 0u; }

__global__ void absmax_rec(const float* __restrict__ rec, unsigned* __restrict__ s) {
  int i = (blockIdx.x * 256 + threadIdx.x) * 4;
  float4 v = *(const float4*)(rec + i);
  float m = fmaxf(fmaxf(fabsf(v.x), fabsf(v.y)), fmaxf(fabsf(v.z), fabsf(v.w)));
  #pragma unroll
  for (int off = 32; off >= 1; off >>= 1) m = fmaxf(m, __shfl_xor(m, off));
  __shared__ float sm[4];
  int l = threadIdx.x & 63, wv = threadIdx.x >> 6;
  if (l == 0) sm[wv] = m;
  __syncthreads();
  if (threadIdx.x == 0) {
    m = fmaxf(fmaxf(sm[0], sm[1]), fmaxf(sm[2], sm[3]));
    atomicMax(s, __float_as_uint(m));
  }
}

// rec [256][768] f32 -> i8 A-fragment layout [48 mt][4 ks][64 lane][16B]
__global__ void conv_rec_i8(const float* __restrict__ rec, const unsigned* __restrict__ sc,
                            char* __restrict__ dst) {
  int idx = blockIdx.x * 256 + threadIdx.x;
  int j = idx & 15, l = (idx >> 4) & 63, sl = idx >> 10;
  int mt = sl >> 2, ks = sl & 3, bi = l & 15, hi = l >> 4;
  float am = __uint_as_float(*sc) + 1e-30f;
  float s = 127.f / am;
  float v = rec[(size_t)(ks * 64 + hi * 16 + j) * NG + mt * 16 + bi] * s;
  int q = __float2int_rn(v);
  q = q > 127 ? 127 : (q < -127 ? -127 : q);
  dst[idx] = (char)q;
}

// ---------------- mega kernel: [scan | gemm | ln] by blockIdx range ----------------
// xws page layout per (g,t): 3072 f16 = 6144 B: [0,4096)B zr pairs (lane*4B), [4096,6144)B h (lane*2B)
// Hq swizzle: granule g of row bc stored at position g ^ (bc<<2)  -> 2-way banks (free)

__global__ __launch_bounds__(1024) void mega(
    const char* __restrict__ rq,        // [48][4][64][16] i8
    const _Float16* __restrict__ xwsS,
    const unsigned* __restrict__ sc,
    float* __restrict__ out,
    float* __restrict__ hg,
    int scanT0,
    const _Float16* __restrict__ xhc,
    const _Float16* __restrict__ kT,
    const float* __restrict__ bias,
    _Float16* __restrict__ xwsG,
    const float* __restrict__ gamma,
    const float* __restrict__ beta,
    int lnT0,
    int nScan, int nGemm)
{
  __shared__ union UU {
    struct { alignas(16) char Hq[2][1024]; } s;
    struct { alignas(16) _Float16 As[128 * 32]; alignas(16) _Float16 Bs[128 * 32]; } g;
  } U;

  int bid = blockIdx.x;
  const int tid = threadIdx.x;

  // ================= SCAN =================
  if (bid < nScan) {
    const int g = bid;
    const int w = tid >> 6, l = tid & 63, bi = l & 15, hi = l >> 4;
    const int bc = bi & 3, qq = bi >> 2;
    const int u = w * 16 + hi * 4 + qq;

    // A-frags: 12 named i32x4 (48 VGPR)
    const i32x4* rp = (const i32x4*)rq;
#define FR(mt, ks) rp[((mt) * 4 + (ks)) * 64 + l]
    i32x4 Az0 = FR(w, 0),      Az1 = FR(w, 1),      Az2 = FR(w, 2),      Az3 = FR(w, 3);
    i32x4 Ar0 = FR(16 + w, 0), Ar1 = FR(16 + w, 1), Ar2 = FR(16 + w, 2), Ar3 = FR(16 + w, 3);
    i32x4 Ah0 = FR(32 + w, 0), Ah1 = FR(32 + w, 1), Ah2 = FR(32 + w, 2), Ah3 = FR(32 + w, 3);
#undef FR
    asm volatile("" : "+v"(Az0), "+v"(Az1), "+v"(Az2), "+v"(Az3),
                      "+v"(Ar0), "+v"(Ar1), "+v"(Ar2), "+v"(Ar3),
                      "+v"(Ah0), "+v"(Ah1), "+v"(Ah2), "+v"(Ah3));

    const float dq = (__uint_as_float(*sc) + 1e-30f) / (127.f * 127.f);

    float h = (scanT0 == 0) ? 0.f : hg[(size_t)(g * 4 + bc) * 256 + u];

    // bank-balanced swizzle: position = granule ^ (bc<<2)
    const int hwa = bc * 256 + ((w ^ (bc << 2)) << 4) + hi * 4 + qq;
    { int q8 = __float2int_rn(h * 127.f); U.s.Hq[0][hwa] = (char)q8; }

    // strength-reduced pointers: advance by one 6144B page per step
    const char* xpz = (const char*)xwsS + (size_t)g * TC * 6144 + tid * 4;
    const char* xph = xpz - tid * 4 + 4096 + tid * 2;
    float* outp = out + ((size_t)(g * 4 + bc) * T_ + scanT0) * U_ + u;

    unsigned nzr = *(const unsigned*)xpz;
    _Float16 nh2 = *(const _Float16*)xph;
    int hrd = 0;   // read-buffer byte offset, toggled by ^1024
    bar_lds();

    #pragma unroll 1
    for (int t = 0; t < TC; ++t) {
      half2_t zrp = __builtin_bit_cast(half2_t, nzr);
      float xzf = (float)zrp[0], xrf = (float)zrp[1], xhf = (float)nh2;
      // unconditional prefetch of next page (last iter over-reads into adjacent ws)
      xpz += 6144; xph += 6144;
      nzr = *(const unsigned*)xpz;
      nh2 = *(const _Float16*)xph;

      const char* hb = &U.s.Hq[0][0] + hrd;
      i32x4 az = {}, ar = {}, ah = {};
#define BADDR(ks) (bc * 256 + ((((ks) * 4 + hi) ^ (bc << 2)) << 4))
      { i32x4 Bf;
        Bf = *(const i32x4*)(hb + BADDR(0));
        az = __builtin_amdgcn_mfma_i32_16x16x64_i8(Az0, Bf, az, 0, 0, 0);
        ar = __builtin_amdgcn_mfma_i32_16x16x64_i8(Ar0, Bf, ar, 0, 0, 0);
        ah = __builtin_amdgcn_mfma_i32_16x16x64_i8(Ah0, Bf, ah, 0, 0, 0);
        Bf = *(const i32x4*)(hb + BADDR(1));
        az = __builtin_amdgcn_mfma_i32_16x16x64_i8(Az1, Bf, az, 0, 0, 0);
        ar = __builtin_amdgcn_mfma_i32_16x16x64_i8(Ar1, Bf, ar, 0, 0, 0);
        ah = __builtin_amdgcn_mfma_i32_16x16x64_i8(Ah1, Bf, ah, 0, 0, 0);
        Bf = *(const i32x4*)(hb + BADDR(2));
        az = __builtin_amdgcn_mfma_i32_16x16x64_i8(Az2, Bf, az, 0, 0, 0);
        ar = __builtin_amdgcn_mfma_i32_16x16x64_i8(Ar2, Bf, ar, 0, 0, 0);
        ah = __builtin_amdgcn_mfma_i32_16x16x64_i8(Ah2, Bf, ah, 0, 0, 0);
        Bf = *(const i32x4*)(hb + BADDR(3));
        az = __builtin_amdgcn_mfma_i32_16x16x64_i8(Az3, Bf, az, 0, 0, 0);
        ar = __builtin_amdgcn_mfma_i32_16x16x64_i8(Ar3, Bf, ar, 0, 0, 0);
        ah = __builtin_amdgcn_mfma_i32_16x16x64_i8(Ah3, Bf, ah, 0, 0, 0);
      }
#undef BADDR

#define SEL4(a) ((qq & 2) ? ((qq & 1) ? (a)[3] : (a)[2]) : ((qq & 1) ? (a)[1] : (a)[0]))
      float pz = (float)SEL4(az) * dq + xzf;
      float pr = (float)SEL4(ar) * dq + xrf;
      float ph = (float)SEL4(ah) * dq + xhf;
#undef SEL4
      float z  = rcpf(1.f + __expf(-pz));
      float r  = rcpf(1.f + __expf(-pr));
      float y  = r * (ph - h) + h;
      float th = 2.f * rcpf(1.f + __expf(-2.f * y)) - 1.f;
      h = z * (h - th) + th;

      *outp = h;
      outp += U_;
      int q8 = __float2int_rn(h * 127.f);
      U.s.Hq[0][(hrd ^ 1024) + hwa] = (char)q8;
      hrd ^= 1024;
      bar_lds();
    }

    hg[(size_t)(g * 4 + bc) * 256 + u] = h;
    return;
  }
  bid -= nScan;

  // ================= GEMM =================
  if (bid < nGemm) {
    const int tile = bid;
    const int mt = tile / 6, nt = tile % 6;
    const int w = tid >> 6, l = tid & 63;
    const int wm = (w & 3) * 32, wn = (w >> 2) * 32;
    const char* Ab = (const char*)xhc + (size_t)mt * 128 * 512;
    const char* Bb = (const char*)kT  + (size_t)nt * 128 * 512;
    f32x4 acc[2][2] = {};

    const bool isA = tid < 512;
    const int cc = isA ? tid : tid - 512;
    const int srow = cc >> 2, sgq = cc & 3;
    const int sgs = sgq ^ ((srow >> 1) & 3);
    const char* sb = isA ? Ab : Bb;
    char* ldsb = (char*)(isA ? U.g.As : U.g.Bs) + cc * 16;

    for (int kt = 0; kt < 8; ++kt) {
      __builtin_amdgcn_global_load_lds(
        (gptr_t)(sb + (size_t)srow * 512 + kt * 64 + sgs * 16),
        (lptr_t)ldsb, 16, 0, 0);
      __syncthreads();

      half8_t av[2], bv[2];
      #pragma unroll
      for (int mi = 0; mi < 2; ++mi) {
        int row = wm + mi * 16 + (l & 15);
        int off = row * 64 + (((l >> 4) ^ ((row >> 1) & 3)) << 4);
        av[mi] = *(const half8_t*)((const char*)U.g.As + off);
      }
      #pragma unroll
      for (int ni = 0; ni < 2; ++ni) {
        int row = wn + ni * 16 + (l & 15);
        int off = row * 64 + (((l >> 4) ^ ((row >> 1) & 3)) << 4);
        bv[ni] = *(const half8_t*)((const char*)U.g.Bs + off);
      }
      #pragma unroll
      for (int mi = 0; mi < 2; ++mi)
        #pragma unroll
        for (int ni = 0; ni < 2; ++ni)
          acc[mi][ni] = __builtin_amdgcn_mfma_f32_16x16x32_f16(av[mi], bv[ni], acc[mi][ni], 0, 0, 0);
      __syncthreads();
    }

    // epilogue: scatter to scan page layout with bias add
    #pragma unroll
    for (int mi = 0; mi < 2; ++mi) {
      #pragma unroll
      for (int ni = 0; ni < 2; ++ni) {
        int c = nt * 128 + wn + ni * 16 + (l & 15);
        int cgate = c >> 8, uu = c & 255;
        int wv = uu >> 4, hq = (uu >> 2) & 3, qv = uu & 3;
        int lane_tid = wv * 64 + (qv << 2) + (hq << 4);
        float bc = bias[c];
        #pragma unroll
        for (int q = 0; q < 4; ++q) {
          int arow = mt * 128 + wm + mi * 16 + ((l >> 4) * 4 + q);
          int b = arow >> 9, tloc = arow & 511;
          int g = b >> 2, bidx = b & 3;
          int lane = lane_tid + bidx;
          size_t page = (size_t)(g * 512 + tloc) * 3072;
          size_t dst = (cgate < 2) ? (page + (size_t)lane * 2 + cgate)
                                   : (page + 2048 + lane);
          xwsG[dst] = (_Float16)(acc[mi][ni][q] + bc);
        }
      }
    }
    return;
  }
  bid -= nGemm;

  // ================= LN (in-place on out) =================
  {
    int rid = bid * 16 + (tid >> 6);
    int l = tid & 63;
    int b = rid >> 9, tl = rid & 511;
    float* p = out + ((size_t)b * T_ + lnT0 + tl) * U_ + l * 4;
    f32x4 v = *(const f32x4*)p;
    float s  = (v[0] + v[1]) + (v[2] + v[3]);
    float s2 = (v[0]*v[0] + v[1]*v[1]) + (v[2]*v[2] + v[3]*v[3]);
    #pragma unroll
    for (int off = 1; off <= 32; off <<= 1) {
      s  += __shfl_xor(s, off);
      s2 += __shfl_xor(s2, off);
    }
    float mu = s * (1.f / 256.f);
    float var = s2 * (1.f / 256.f) - mu * mu;
    float rs = rsqrtf(var + 1e-6f);
    f32x4 gm = *(const f32x4*)(gamma + l * 4);
    f32x4 bt = *(const f32x4*)(beta + l * 4);
    f32x4 o;
    o[0] = (v[0] - mu) * rs * gm[0] + bt[0];
    o[1] = (v[1] - mu) * rs * gm[1] + bt[1];
    o[2] = (v[2] - mu) * rs * gm[2] + bt[2];
    o[3] = (v[3] - mu) * rs * gm[3] + bt[3];
    *(f32x4*)p = o;
  }
}

// ---------------- launcher ----------------
extern "C" void kernel_launch(void* const* d_in, const int* in_sizes, int n_in,
                              void* d_out, int out_size, void* d_ws, size_t ws_size,
                              hipStream_t stream) {
  const float* x     = (const float*)d_in[0];
  const float* kern  = (const float*)d_in[1];
  const float* rec   = (const float*)d_in[2];
  const float* bias  = (const float*)d_in[3];
  const float* gamma = (const float*)d_in[4];
  const float* beta  = (const float*)d_in[5];
  float* out = (float*)d_out;
  char* ws = (char*)d_ws;

  const size_t XWS = 50331648;  // 16*512*3072*2
  const bool pipe = (ws_size >= 118096000ull);

  _Float16* xwsA = (_Float16*)ws;
  _Float16* xwsB = pipe ? (_Float16*)(ws + XWS) : xwsA;
  size_t o = pipe ? 2 * XWS : XWS;
  _Float16* xhc = (_Float16*)(ws + o);           o += 16777216;
  _Float16* kT  = (_Float16*)(ws + o);           o += 393216;
  char*     rq  = (char*)    (ws + o);           o += 196608;
  unsigned* sc  = (unsigned*)(ws + o);           o += 128;
  float*    hg  = (float*)   (ws + o);

  init_scale<<<1, 64, 0, stream>>>(sc);
  absmax_rec<<<192, 256, 0, stream>>>(rec, sc);
  conv_T<<<768, 256, 0, stream>>>(kern, kT);
  conv_rec_i8<<<768, 256, 0, stream>>>(rec, sc, rq);

  if (pipe) {
    conv_x_chunk<<<4096, 256, 0, stream>>>(x, xhc, 0);
    mega<<<GB_GEMM, 1024, 0, stream>>>(rq, xwsA, sc, out, hg, 0,
                                       xhc, kT, bias, xwsA, gamma, beta, 0,
                                       0, GB_GEMM);
    conv_x_chunk<<<4096, 256, 0, stream>>>(x, xhc, TC);
    mega<<<GB_SCAN + GB_GEMM, 1024, 0, stream>>>(rq, xwsA, sc, out, hg, 0,
                                       xhc, kT, bias, xwsB, gamma, beta, 0,
                                       GB_SCAN, GB_GEMM);
    conv_x_chunk<<<4096, 256, 0, stream>>>(x, xhc, 2 * TC);
    mega<<<GB_SCAN + GB_GEMM + GB_LN, 1024, 0, stream>>>(rq, xwsB, sc, out, hg, TC,
                                       xhc, kT, bias, xwsA, gamma, beta, 0,
                                       GB_SCAN, GB_GEMM);
    conv_x_chunk<<<4096, 256, 0, stream>>>(x, xhc, 3 * TC);
    mega<<<GB_SCAN + GB_GEMM + GB_LN, 1024, 0, stream>>>(rq, xwsA, sc, out, hg, 2 * TC,
                                       xhc, kT, bias, xwsB, gamma, beta, TC,
                                       GB_SCAN, GB_GEMM);
    mega<<<GB_SCAN + GB_LN, 1024, 0, stream>>>(rq, xwsB, sc, out, hg, 3 * TC,
                                       xhc, kT, bias, xwsA, gamma, beta, 2 * TC,
                                       GB_SCAN, 0);
    mega<<<GB_LN, 1024, 0, stream>>>(rq, xwsA, sc, out, hg, 0,
                                       xhc, kT, bias, xwsA, gamma, beta, 3 * TC,
                                       0, 0);
  } else {
    for (int c = 0; c < NCHUNK; ++c) {
      int t0 = c * TC;
      conv_x_chunk<<<4096, 256, 0, stream>>>(x, xhc, t0);
      mega<<<GB_GEMM, 1024, 0, stream>>>(rq, xwsA, sc, out, hg, t0,
                                         xhc, kT, bias, xwsA, gamma, beta, t0,
                                         0, GB_GEMM);
      mega<<<GB_SCAN, 1024, 0, stream>>>(rq, xwsA, sc, out, hg, t0,
                                         xhc, kT, bias, xwsA, gamma, beta, t0,
                                         GB_SCAN, 0);
      mega<<<GB_LN, 1024, 0, stream>>>(rq, xwsA, sc, out, hg, t0,
                                       xhc, kT, bias, xwsA, gamma, beta, t0,
                                       0, 0);
    }
  }
}